// Round 18
// baseline (374.605 us; speedup 1.0000x reference)
//
#include <hip/hip_runtime.h>
#include <hip/hip_bf16.h>

#define DD 256
#define KC 1024
#define NT 8      // 8 tiles of 128 codes in both passes

typedef __attribute__((ext_vector_type(4))) float f32x4;
typedef __attribute__((ext_vector_type(16))) float f32x16;
typedef __attribute__((ext_vector_type(8))) short bf16x8;

#define MFMA32 __builtin_amdgcn_mfma_f32_32x32x16_bf16

// Raw barrier: LDS ordering only (T4). Global stores/prefetch stay in flight.
#define BAR() do { \
    asm volatile("s_waitcnt lgkmcnt(0)" ::: "memory"); \
    __builtin_amdgcn_s_barrier(); \
    __builtin_amdgcn_sched_barrier(0); \
} while (0)

static __device__ __forceinline__ short f2bf(float f) {
    union { float f; unsigned u; } v; v.f = f;
    unsigned u = v.u;
    unsigned r = u + 0x7fffu + ((u >> 16) & 1u);
    return (short)(r >> 16);
}
static __device__ __forceinline__ float bf2f(short s) {
    union { unsigned u; float f; } v;
    v.u = ((unsigned)(unsigned short)s) << 16;
    return v.f;
}
static __device__ __forceinline__ unsigned pk2(float a, float b) {
    return (unsigned)(unsigned short)f2bf(a) |
           ((unsigned)(unsigned short)f2bf(b) << 16);
}

// ---------------------------------------------------------------------------
// prep: W fp32 [1024][256] -> wbf bf16 [1024][256], wtbf bf16 [256][1024],
//       wsq[k] = sum_d W[k][d]^2 / 256
// ---------------------------------------------------------------------------
__global__ void prep_kernel(const float* __restrict__ w, short* __restrict__ wbf,
                            short* __restrict__ wtbf, float* __restrict__ wsq) {
    const int cod = blockIdx.x;
    const int d   = threadIdx.x;           // 256 threads
    float v = w[cod * DD + d];
    short b = f2bf(v);
    wbf[cod * DD + d] = b;
    wtbf[d * KC + cod] = b;
    float s = v * v;
    #pragma unroll
    for (int m = 32; m >= 1; m >>= 1) s += __shfl_xor(s, m, 64);
    __shared__ float ps[4];
    const int wave = threadIdx.x >> 6, lane = threadIdx.x & 63;
    if (lane == 0) ps[wave] = s;
    __syncthreads();
    if (threadIdx.x == 0) {
        wsq[cod] = (ps[0] + ps[1] + ps[2] + ps[3]) * (1.0f / (float)DD);
    }
}

// ---------------------------------------------------------------------------
// Fused kernel, 64 rows/block, 512 thr, 8 waves = rg[2 row-halves of 32] x
// cg[4 code-strips of 32]. 32x32x16 MFMA, 8 tiles of 128 codes per pass.
// Fragment layouts (32x32x16 bf16): A: row=l&31, k=(l>>5)*8+i;
//   B: col=l&31, k=(l>>5)*8+i; C/D: col=l&31, row=(reg&3)+8*(reg>>2)+4*(l>>5)
//   (C/D formula HW-verified, m74/m101).
// LDS: ubuf 67.6 KB (xs [64][264] / wt [128][264] / wtT [256][132] / quant
//   bounce [64][257]f32, time-multiplexed) + et dbuf 2x16.9 KB. Row strides
//   264/132 shorts (odd granule count) rotate banks per row: no XOR swizzle
//   needed; all staging identities chosen conflict-free (checked per pattern).
// LAUNCH BOUNDS (512,2): NEVER 4 waves/EU — epk spills wholesale
//   (R10/R11/R15 3x confirmed). Peak regs ~190 < 256.
// ---------------------------------------------------------------------------
__global__ __launch_bounds__(512, 2) void fused_kernel(
    const float* __restrict__ x, const short* __restrict__ wbf,
    const short* __restrict__ wtbf, const float* __restrict__ wsq,
    float* __restrict__ qdist, float* __restrict__ quant)
{
    __shared__ short ubuf[128 * 264];     // 67.6 KB multi-purpose
    __shared__ short et_[2][64 * 132];    // 16.9 KB each: q bf16 [row][128+4pad]
    __shared__ float red_[4][64];
    __shared__ float invs_[64];

    const int t   = threadIdx.x;
    const int w   = t >> 6, l = t & 63;
    const int l31 = l & 31, h = l >> 5;
    const int rg  = w >> 2, cg = w & 3;
    const long rowbase = (long)blockIdx.x * 64;

    // staging identities
    const int sc = t >> 2, sg = t & 3;    // wt: code 0..127, 8 granules (sg+4j)
    const int td = t >> 1, tg = t & 1;    // wtT: d 0..255, 8 granules (tg+2j)

    // ---- issue wt tile0 loads ----
    bf16x8 wpf[8];
    {
        const short* p = wbf + (size_t)sc * DD;
        #pragma unroll
        for (int j = 0; j < 8; j++) wpf[j] = *(const bf16x8*)(p + (sg + 4*j) * 8);
    }

    // ---- stage x -> ubuf [64][264] (coalesced, conflict-free) ----
    {
        const int xr = t >> 3, xg = t & 7;
        const float* xp = x + (rowbase + xr) * DD;
        #pragma unroll
        for (int j = 0; j < 4; j++) {
            const int g = xg + 8*j;
            f32x4 v0 = *(const f32x4*)(xp + g*8);
            f32x4 v1 = *(const f32x4*)(xp + g*8 + 4);
            bf16x8 b;
            b[0]=f2bf(v0[0]); b[1]=f2bf(v0[1]); b[2]=f2bf(v0[2]); b[3]=f2bf(v0[3]);
            b[4]=f2bf(v1[0]); b[5]=f2bf(v1[1]); b[6]=f2bf(v1[2]); b[7]=f2bf(v1[3]);
            *(bf16x8*)((char*)ubuf + xr * 528 + g * 16) = b;
        }
    }
    BAR();

    // ---- xa frags: A row = rg*32 + l31, k-chunk = ks*16 + h*8 ----
    bf16x8 xa[16];
    #pragma unroll
    for (int ks = 0; ks < 16; ks++)
        xa[ks] = *(const bf16x8*)((char*)ubuf + (rg*32 + l31) * 528 + ks*32 + h*16);
    BAR();   // xa reads done; ubuf free for wt staging

    float wscur = wsq[cg * 32 + l31];
    float wsn = 0.f;
    float rs[16];
    #pragma unroll
    for (int j = 0; j < 16; j++) rs[j] = 0.f;
    unsigned epk[NT][8];                  // packed bf16 e — VGPRs only

    // =================== PASS 1: scores (single-buffer wt, 2 BAR/tile) =====
    #pragma unroll
    for (int i = 0; i < NT; i++) {
        // write staged regs -> wt [128][264]
        {
            char* wb = (char*)ubuf + sc * 528;
            #pragma unroll
            for (int j = 0; j < 8; j++)
                *(bf16x8*)(wb + (sg + 4*j) * 16) = wpf[j];
        }
        BAR();                            // wt visible (wpf regs now dead)

        // compute: 16 k-steps, 2 MFMA chains
        f32x16 sA, sB;
        #pragma unroll
        for (int j = 0; j < 16; j++) { sA[j] = 0.f; sB[j] = 0.f; }
        const char* wrow = (char*)ubuf + (cg*32 + l31) * 528 + h*16;
        #pragma unroll
        for (int ks = 0; ks < 16; ks += 2) {
            bf16x8 b0 = *(const bf16x8*)(wrow + ks*32);
            bf16x8 b1 = *(const bf16x8*)(wrow + ks*32 + 32);
            sA = MFMA32(xa[ks],     b0, sA, 0, 0, 0);
            sB = MFMA32(xa[ks + 1], b1, sB, 0, 0, 0);
        }

        // issue tile i+1 loads (in flight across exp + next stage)
        if (i < NT - 1) {
            const short* p = wbf + (size_t)((i + 1) * 128 + sc) * DD;
            #pragma unroll
            for (int j = 0; j < 8; j++) wpf[j] = *(const bf16x8*)(p + (sg + 4*j) * 8);
            wsn = wsq[(i + 1) * 128 + cg * 32 + l31];
        }

        #pragma unroll
        for (int p2 = 0; p2 < 8; p2++) {
            float e0 = __expf((sA[2*p2]   + sB[2*p2])   * (1.0f/128.0f) - wscur);
            float e1 = __expf((sA[2*p2+1] + sB[2*p2+1]) * (1.0f/128.0f) - wscur);
            rs[2*p2]   += e0;
            rs[2*p2+1] += e1;
            epk[i][p2] = pk2(e0, e1);
        }
        wscur = wsn;
        BAR();                            // all wt reads done before next stage
    }

    // ---- issue wtT tile0 loads early (cover under reduction) ----
    bf16x8 tpf[8];
    {
        const short* p = wtbf + (size_t)td * KC;
        #pragma unroll
        for (int j = 0; j < 8; j++) tpf[j] = *(const bf16x8*)(p + (tg + 2*j) * 8);
    }

    // ---- rowsum reduce -> invs ----
    #pragma unroll
    for (int m = 1; m <= 16; m <<= 1)
        #pragma unroll
        for (int j = 0; j < 16; j++) rs[j] += __shfl_xor(rs[j], m, 64);
    if (l31 == 0) {
        #pragma unroll
        for (int j = 0; j < 16; j++)
            red_[cg][rg*32 + (j & 3) + 8*(j >> 2) + 4*h] = rs[j];
    }
    __syncthreads();
    if (t < 64) invs_[t] = 1.0f / (red_[0][t] + red_[1][t] + red_[2][t] + red_[3][t]);
    __syncthreads();

    float inv16[16];
    #pragma unroll
    for (int j = 0; j < 16; j++)
        inv16[j] = invs_[rg*32 + (j & 3) + 8*(j >> 2) + 4*h];

    f32x16 uacc[2];   // PV transposed: D[d][out-row], rowg = out-row half
    #pragma unroll
    for (int j = 0; j < 16; j++) { uacc[0][j] = 0.f; uacc[1][j] = 0.f; }

    float* qbase = qdist + rowbase * KC;
    const int qr = t >> 3, qs = t & 7;    // qdist identity: row, 16-code segment

    // =================== PASS 2: PV + outputs (2 BAR/tile) =================
    #pragma unroll
    for (int k = 0; k < NT; k++) {
        const int b = k & 1;
        // et write: normalized q from epk[k]; wave writes its 32x32 block
        {
            const int col = cg * 32 + l31;
            #pragma unroll
            for (int p2 = 0; p2 < 8; p2++) {
                const int r0 = rg*32 + 2*(p2 & 1) + 8*(p2 >> 1) + 4*h;
                const unsigned pk = epk[k][p2];
                et_[b][r0 * 132 + col]       = f2bf(bf2f((short)(pk & 0xffff)) * inv16[2*p2]);
                et_[b][(r0 + 1) * 132 + col] = f2bf(bf2f((short)(pk >> 16))    * inv16[2*p2 + 1]);
            }
        }
        // stage wtT tile k -> ubuf [256][132]
        {
            char* tb = (char*)ubuf + td * 264;
            #pragma unroll
            for (int j = 0; j < 8; j++)
                *(bf16x8*)(tb + (tg + 2*j) * 16) = tpf[j];
        }
        if (k < NT - 1) {                 // load wtT tile k+1 (in flight)
            const short* p = wtbf + (size_t)td * KC + (k + 1) * 128;
            #pragma unroll
            for (int j = 0; j < 8; j++) tpf[j] = *(const bf16x8*)(p + (tg + 2*j) * 8);
        }
        BAR();                            // et + wtT visible

        // qdist store: thread reads 16 codes (32B) of its row, stores 4 f32x4
        {
            const char* ep = (const char*)et_[b] + qr * 264 + qs * 32;
            bf16x8 e0 = *(const bf16x8*)ep;
            bf16x8 e1 = *(const bf16x8*)(ep + 16);
            float* qd = qbase + (size_t)qr * KC + (size_t)k * 128 + qs * 16;
            f32x4 o;
            o[0]=bf2f(e0[0]); o[1]=bf2f(e0[1]); o[2]=bf2f(e0[2]); o[3]=bf2f(e0[3]);
            *(f32x4*)(qd) = o;
            o[0]=bf2f(e0[4]); o[1]=bf2f(e0[5]); o[2]=bf2f(e0[6]); o[3]=bf2f(e0[7]);
            *(f32x4*)(qd + 4) = o;
            o[0]=bf2f(e1[0]); o[1]=bf2f(e1[1]); o[2]=bf2f(e1[2]); o[3]=bf2f(e1[3]);
            *(f32x4*)(qd + 8) = o;
            o[0]=bf2f(e1[4]); o[1]=bf2f(e1[5]); o[2]=bf2f(e1[6]); o[3]=bf2f(e1[7]);
            *(f32x4*)(qd + 12) = o;
        }

        // PV: A = wtT (d-rows w*32+l31), B = et (out-rows), D[d][out-row]
        {
            const char* arow = (char*)ubuf + (w*32 + l31) * 264 + h * 16;
            const char* eb   = (const char*)et_[b];
            #pragma unroll
            for (int ks = 0; ks < 8; ks++) {
                bf16x8 av = *(const bf16x8*)(arow + ks * 32);
                bf16x8 b0 = *(const bf16x8*)(eb + (l31)      * 264 + ks*32 + h*16);
                bf16x8 b1 = *(const bf16x8*)(eb + (32 + l31) * 264 + ks*32 + h*16);
                uacc[0] = MFMA32(av, b0, uacc[0], 0, 0, 0);
                uacc[1] = MFMA32(av, b1, uacc[1], 0, 0, 0);
            }
        }
        BAR();                            // reads done before next overwrite
    }

    // ===== quant epilogue: LDS bounce [64][257] f32 -> coalesced stores ====
    {
        float* ob = (float*)ubuf;         // 64*257*4 = 65.8 KB <= 67.6 KB
        #pragma unroll
        for (int rowg = 0; rowg < 2; rowg++)
            #pragma unroll
            for (int j = 0; j < 16; j++) {
                const int d = w*32 + (j & 3) + 8*(j >> 2) + 4*h;
                ob[(rowg*32 + l31) * 257 + d] = uacc[rowg][j];
            }
        BAR();
        const int orow = t >> 3, oseg = t & 7;
        const float* src = ob + orow * 257 + oseg * 4;
        float* dst = quant + (rowbase + orow) * DD + oseg * 4;
        #pragma unroll
        for (int q4 = 0; q4 < 8; q4++)
            *(f32x4*)(dst + q4 * 32) = *(const f32x4*)(src + q4 * 32);
    }
}

// ---------------------------------------------------------------------------
extern "C" void kernel_launch(void* const* d_in, const int* in_sizes, int n_in,
                              void* d_out, int out_size, void* d_ws, size_t ws_size,
                              hipStream_t stream) {
    const float* x = (const float*)d_in[0];
    const float* w = (const float*)d_in[1];
    float* out = (float*)d_out;

    const int nrows = in_sizes[0] / DD;          // 65536
    float* quant = out;                          // [nrows][256]
    float* qdist = out + (size_t)nrows * DD;     // [nrows][1024]

    short* wbf  = (short*)d_ws;                  // 1024*256 bf16 = 512 KB
    short* wtbf = wbf + (size_t)KC * DD;         // 256*1024 bf16 = 512 KB
    float* wsq  = (float*)(wtbf + (size_t)DD * KC);  // 1024 fp32

    prep_kernel<<<KC, DD, 0, stream>>>(w, wbf, wtbf, wsq);
    fused_kernel<<<nrows / 64, 512, 0, stream>>>(x, wbf, wtbf, wsq, qdist, quant);
}

// Round 19
// 253.633 us; speedup vs baseline: 1.4770x; 1.4770x over previous
//
#include <hip/hip_runtime.h>
#include <hip/hip_bf16.h>

#define DD 256
#define KC 1024
#define NT1 16    // pass-1: 16 tiles of 64 codes
#define NT2 32    // pass-2: 32 tiles of 32 codes

typedef __attribute__((ext_vector_type(4))) float f32x4;
typedef __attribute__((ext_vector_type(8))) short bf16x8;

#define MFMA16 __builtin_amdgcn_mfma_f32_16x16x32_bf16

// Raw barrier: LDS ordering only (T4). Global stores/prefetch stay in flight.
#define BAR() do { \
    asm volatile("s_waitcnt lgkmcnt(0)" ::: "memory"); \
    __builtin_amdgcn_s_barrier(); \
    __builtin_amdgcn_sched_barrier(0); \
} while (0)

static __device__ __forceinline__ short f2bf(float f) {
    union { float f; unsigned u; } v; v.f = f;
    unsigned u = v.u;
    unsigned r = u + 0x7fffu + ((u >> 16) & 1u);
    return (short)(r >> 16);
}
static __device__ __forceinline__ float bf2f(short s) {
    union { unsigned u; float f; } v;
    v.u = ((unsigned)(unsigned short)s) << 16;
    return v.f;
}
static __device__ __forceinline__ unsigned pk2(float a, float b) {
    return (unsigned)(unsigned short)f2bf(a) |
           ((unsigned)(unsigned short)f2bf(b) << 16);
}

// ---------------------------------------------------------------------------
// prep: W fp32 [1024][256] -> wbf bf16 [1024][256], wtbf bf16 [256][1024],
//       wsq[k] = sum_d W[k][d]^2 / 256
// ---------------------------------------------------------------------------
__global__ void prep_kernel(const float* __restrict__ w, short* __restrict__ wbf,
                            short* __restrict__ wtbf, float* __restrict__ wsq) {
    const int cod = blockIdx.x;
    const int d   = threadIdx.x;           // 256 threads
    float v = w[cod * DD + d];
    short b = f2bf(v);
    wbf[cod * DD + d] = b;
    wtbf[d * KC + cod] = b;
    float s = v * v;
    #pragma unroll
    for (int m = 32; m >= 1; m >>= 1) s += __shfl_xor(s, m, 64);
    __shared__ float ps[4];
    const int wave = threadIdx.x >> 6, lane = threadIdx.x & 63;
    if (lane == 0) ps[wave] = s;
    __syncthreads();
    if (threadIdx.x == 0) {
        wsq[cod] = (ps[0] + ps[1] + ps[2] + ps[3]) * (1.0f / (float)DD);
    }
}

// ---------------------------------------------------------------------------
// Fused kernel, 32 rows/block, 512 thr, 8 waves = rg[2 row-strips of 16] x
// cg[4 code-strips of 16].
// KEY: per-thread state ~126 unified regs (epk halved to 32 via BM=32) so
// the HW register tier gives 16 waves/CU (R9 precedent: 96+32 -> 42% occ);
// every >=160-reg variant measured only 8 waves/CU (22%).
// PASS 1: 16 tiles x 64 codes, wt_ single-buffered 32 KB (2 BAR/tile),
//   R16's proven staging + XOR swizzle. e packed bf16 in 32 VGPRs.
// PASS 2: R12's PV core verbatim at 32 rows (1 BAR/tile).
// LDS 70.8 KB -> 2 blocks/CU. launch_bounds (512,4): state FITS 128 now
// (earlier (512,4) spills were with ~190-reg state; check WRITE_SIZE).
// ---------------------------------------------------------------------------
__global__ __launch_bounds__(512, 4) void fused_kernel(
    const float* __restrict__ x, const short* __restrict__ wbf,
    const short* __restrict__ wtbf, const float* __restrict__ wsq,
    float* __restrict__ qdist, float* __restrict__ quant)
{
    __shared__ short wt_[64 * DD];        // 32 KB single buffer: [code][256 d]
    __shared__ short wtT_[2][128 * 64];   // 16 KB each: superrow layout, swizzled
    __shared__ short et_[2][32 * 36];     // 2.25 KB each: q bf16 [row][32+4pad]
    __shared__ float red_[4][32];
    __shared__ float invs_[32];

    const int t   = threadIdx.x;
    const int w   = t >> 6, l = t & 63;
    const int lhi = l >> 4, llo = l & 15;
    const int rg  = w >> 2, cg = w & 3;
    const long rowbase = (long)blockIdx.x * 32;

    // pass-1 staging identity: 64-code tile = 32 KB; 64 B/thread
    const int sc1 = t >> 3;              // code 0..63
    const int gq  = (t & 7) * 4;         // granule base 0,4,...,28
    // pass-2 wtT staging identity (R12, proven)
    const int sd  = t >> 1;              // d 0..255
    const int sg2 = (t & 1) * 2;
    const int ssr = sd >> 1;
    const int shb = (sd & 1) * 4;

    bf16x8 wpf[4];

    // ---- issue wt tile0 loads ----
    {
        const short* p = wbf + (size_t)sc1 * DD + gq * 8;
        #pragma unroll
        for (int j = 0; j < 4; j++) wpf[j] = *(const bf16x8*)(p + j * 8);
    }

    // ---- x fragments: wave rows rg*16 + llo, k-chunk lhi*8 ----
    bf16x8 xa[8];
    {
        const float* xr = x + (rowbase + rg * 16 + llo) * DD + lhi * 8;
        #pragma unroll
        for (int kk = 0; kk < 8; kk++) {
            f32x4 v0 = *(const f32x4*)(xr + kk * 32);
            f32x4 v1 = *(const f32x4*)(xr + kk * 32 + 4);
            bf16x8 b;
            b[0]=f2bf(v0[0]); b[1]=f2bf(v0[1]); b[2]=f2bf(v0[2]); b[3]=f2bf(v0[3]);
            b[4]=f2bf(v1[0]); b[5]=f2bf(v1[1]); b[6]=f2bf(v1[2]); b[7]=f2bf(v1[3]);
            xa[kk] = b;
        }
    }

    const int mycode = cg * 16 + llo;     // code within 64-tile, 0..63
    const int cswz   = mycode & 7;
    float wscur  = wsq[mycode];
    float wsnext = wsq[64 + mycode];

    float rs[4] = {0.f, 0.f, 0.f, 0.f};
    unsigned epk[NT1][2];                 // 32 VGPRs — the halved e state

    // =================== PASS 1: scores (single-buffer wt_) ================
    #pragma unroll
    for (int i = 0; i < NT1; i++) {
        if (i) BAR();                     // all reads of tile i-1 done
        {
            char* wb = (char*)wt_ + sc1 * 512;
            #pragma unroll
            for (int j = 0; j < 4; j++)
                *(bf16x8*)(wb + (((gq + j) ^ (sc1 & 7)) << 4)) = wpf[j];
        }
        if (i < NT1 - 1) {                // issue tile i+1 loads (in flight)
            const short* p = wbf + (size_t)((i + 1) * 64 + sc1) * DD + gq * 8;
            #pragma unroll
            for (int j = 0; j < 4; j++) wpf[j] = *(const bf16x8*)(p + j * 8);
        }
        BAR();                            // wt_ visible
        char* wb2 = (char*)wt_ + mycode * 512;
        f32x4 sacc = {0.f, 0.f, 0.f, 0.f};
        #pragma unroll
        for (int kk = 0; kk < 8; kk++) {
            bf16x8 bb = *(const bf16x8*)(wb2 + (((kk * 4 + lhi) ^ cswz) << 4));
            sacc = MFMA16(xa[kk], bb, sacc, 0, 0, 0);
        }
        float e0 = __expf(sacc[0] * (1.0f / 128.0f) - wscur);
        float e1 = __expf(sacc[1] * (1.0f / 128.0f) - wscur);
        float e2 = __expf(sacc[2] * (1.0f / 128.0f) - wscur);
        float e3 = __expf(sacc[3] * (1.0f / 128.0f) - wscur);
        rs[0] += e0; rs[1] += e1; rs[2] += e2; rs[3] += e3;
        epk[i][0] = pk2(e0, e1);
        epk[i][1] = pk2(e2, e3);
        wscur = wsnext;
        if (i < NT1 - 2) wsnext = wsq[(i + 2) * 64 + mycode];
    }

    // ---- issue wtT tile0 loads early (cover under reduction) ----
    bf16x8 tpf0, tpf1;
    { const short* p = wtbf + (size_t)sd * KC + sg2 * 8;
      tpf0 = *(const bf16x8*)p; tpf1 = *(const bf16x8*)(p + 8); }

    // ---- rowsum reduce (over llo lanes) -> invs across 4 cg strips ----
    #pragma unroll
    for (int m = 1; m <= 8; m <<= 1)
        #pragma unroll
        for (int r = 0; r < 4; r++) rs[r] += __shfl_xor(rs[r], m, 64);
    if (llo == 0) {
        #pragma unroll
        for (int r = 0; r < 4; r++) red_[cg][rg * 16 + lhi * 4 + r] = rs[r];
    }
    __syncthreads();
    if (t < 32) invs_[t] = 1.0f / (red_[0][t] + red_[1][t] + red_[2][t] + red_[3][t]);
    __syncthreads();

    float inv4[4];
    #pragma unroll
    for (int r = 0; r < 4; r++) inv4[r] = invs_[rg * 16 + lhi * 4 + r];

    f32x4 uacc[2][2];   // transposed PV: D[d-subtile][row-subtile], 16 AGPR
    #pragma unroll
    for (int a = 0; a < 2; a++)
        #pragma unroll
        for (int b = 0; b < 2; b++) uacc[a][b] = (f32x4){0.f, 0.f, 0.f, 0.f};

    float* qbase = qdist + rowbase * KC;
    const int myrow0 = rg * 16 + lhi * 4;
    const int ci     = (cg & 1) * 16 + llo;   // code-in-32-tile for et writes
    const int chalf  = cg >> 1;               // which 32-half this wave holds
    const int qrow = t >> 3, c4 = (t & 7) * 4; // qdist identity (t<256 active)

    // =================== PASS 2: PV + outputs (R12 core, 1 BAR/tile) =======
    #pragma unroll
    for (int k = 0; k < NT2; k++) {
        const int b = k & 1;
        // et write: waves whose cg-half owns codes [k*32, k*32+32)
        if (chalf == (k & 1)) {
            const unsigned p0 = epk[k >> 1][0], p1 = epk[k >> 1][1];
            et_[b][(myrow0 + 0) * 36 + ci] = f2bf(bf2f((short)(p0 & 0xffff)) * inv4[0]);
            et_[b][(myrow0 + 1) * 36 + ci] = f2bf(bf2f((short)(p0 >> 16))    * inv4[1]);
            et_[b][(myrow0 + 2) * 36 + ci] = f2bf(bf2f((short)(p1 & 0xffff)) * inv4[2]);
            et_[b][(myrow0 + 3) * 36 + ci] = f2bf(bf2f((short)(p1 >> 16))    * inv4[3]);
        }
        // stage wtT tile k -> wtT_[b]
        {
            char* tb = (char*)wtT_[b] + ssr * 128;
            *(bf16x8*)(tb + (((shb + sg2    ) ^ (ssr & 7)) << 4)) = tpf0;
            *(bf16x8*)(tb + (((shb + sg2 + 1) ^ (ssr & 7)) << 4)) = tpf1;
        }
        if (k < NT2 - 1) {                // load wtT tile k+1
            const short* p = wtbf + (size_t)sd * KC + (k + 1) * 32 + sg2 * 8;
            tpf0 = *(const bf16x8*)p; tpf1 = *(const bf16x8*)(p + 8);
        }
        BAR();
        // qdist store (t<256): full-line f32x4 per 8-lane row group
        if (t < 256) {
            const char* ep = (const char*)et_[b] + qrow * 72 + c4 * 2;
            unsigned u0 = *(const unsigned*)ep;
            unsigned u1 = *(const unsigned*)(ep + 4);
            f32x4 o;
            o[0] = bf2f((short)(u0 & 0xffff)); o[1] = bf2f((short)(u0 >> 16));
            o[2] = bf2f((short)(u1 & 0xffff)); o[3] = bf2f((short)(u1 >> 16));
            *(f32x4*)(qbase + (size_t)qrow * KC + (size_t)k * 32 + c4) = o;
        }
        // PV from et_[b] + wtT_[b]; wave owns d-cols [w*32, w*32+32)
        bf16x8 bb0, bb1;
        {
            const int d0 = w * 32 + llo;
            bb0 = *(const bf16x8*)((char*)wtT_[b] + (d0 >> 1) * 128 +
                    (((((d0 & 1) << 2) + lhi) ^ ((d0 >> 1) & 7)) << 4));
            const int d1 = w * 32 + 16 + llo;
            bb1 = *(const bf16x8*)((char*)wtT_[b] + (d1 >> 1) * 128 +
                    (((((d1 & 1) << 2) + lhi) ^ ((d1 >> 1) & 7)) << 4));
        }
        #pragma unroll
        for (int rowg = 0; rowg < 2; rowg++) {
            bf16x8 aa = *(const bf16x8*)((char*)et_[b] + (rowg * 16 + llo) * 72 + lhi * 16);
            uacc[rowg][0] = MFMA16(bb0, aa, uacc[rowg][0], 0, 0, 0);
            uacc[rowg][1] = MFMA16(bb1, aa, uacc[rowg][1], 0, 0, 0);
        }
    }

    // quant stores: uacc[rowg][dg] = D[d][row] -> f32x4 along d (verified map)
    #pragma unroll
    for (int rowg = 0; rowg < 2; rowg++)
        #pragma unroll
        for (int dg = 0; dg < 2; dg++)
            *(f32x4*)(quant + (rowbase + rowg * 16 + llo) * DD + w * 32 + dg * 16 + lhi * 4)
                = uacc[rowg][dg];
}

// ---------------------------------------------------------------------------
extern "C" void kernel_launch(void* const* d_in, const int* in_sizes, int n_in,
                              void* d_out, int out_size, void* d_ws, size_t ws_size,
                              hipStream_t stream) {
    const float* x = (const float*)d_in[0];
    const float* w = (const float*)d_in[1];
    float* out = (float*)d_out;

    const int nrows = in_sizes[0] / DD;          // 65536
    float* quant = out;                          // [nrows][256]
    float* qdist = out + (size_t)nrows * DD;     // [nrows][1024]

    short* wbf  = (short*)d_ws;                  // 1024*256 bf16 = 512 KB
    short* wtbf = wbf + (size_t)KC * DD;         // 256*1024 bf16 = 512 KB
    float* wsq  = (float*)(wtbf + (size_t)DD * KC);  // 1024 fp32

    prep_kernel<<<KC, DD, 0, stream>>>(w, wbf, wtbf, wsq);
    fused_kernel<<<nrows / 32, 512, 0, stream>>>(x, wbf, wtbf, wsq, qdist, quant);
}

// Round 20
// 195.793 us; speedup vs baseline: 1.9133x; 1.2954x over previous
//
#include <hip/hip_runtime.h>
#include <hip/hip_bf16.h>

#define DD 256
#define KC 1024
#define NT 32     // 32 tiles of 32 codes

typedef __attribute__((ext_vector_type(4))) float f32x4;
typedef __attribute__((ext_vector_type(8))) short bf16x8;

// Raw barrier: LDS ordering only (T4). Global stores/prefetch stay in flight.
#define BAR() do { \
    asm volatile("s_waitcnt lgkmcnt(0)" ::: "memory"); \
    __builtin_amdgcn_s_barrier(); \
    __builtin_amdgcn_sched_barrier(0); \
} while (0)

static __device__ __forceinline__ short f2bf(float f) {
    union { float f; unsigned u; } v; v.f = f;
    unsigned u = v.u;
    unsigned r = u + 0x7fffu + ((u >> 16) & 1u);
    return (short)(r >> 16);
}
static __device__ __forceinline__ float bf2f(short s) {
    union { unsigned u; float f; } v;
    v.u = ((unsigned)(unsigned short)s) << 16;
    return v.f;
}
static __device__ __forceinline__ unsigned pk2(float a, float b) {
    return (unsigned)(unsigned short)f2bf(a) |
           ((unsigned)(unsigned short)f2bf(b) << 16);
}

// ---------------------------------------------------------------------------
// prep: W fp32 [1024][256] -> wbf bf16 [1024][256], wtbf bf16 [256][1024],
//       wsq[k] = sum_d W[k][d]^2 / 256
// ---------------------------------------------------------------------------
__global__ void prep_kernel(const float* __restrict__ w, short* __restrict__ wbf,
                            short* __restrict__ wtbf, float* __restrict__ wsq) {
    const int cod = blockIdx.x;
    const int d   = threadIdx.x;           // 256 threads
    float v = w[cod * DD + d];
    short b = f2bf(v);
    wbf[cod * DD + d] = b;
    wtbf[d * KC + cod] = b;
    float s = v * v;
    #pragma unroll
    for (int m = 32; m >= 1; m >>= 1) s += __shfl_xor(s, m, 64);
    __shared__ float ps[4];
    const int wave = threadIdx.x >> 6, lane = threadIdx.x & 63;
    if (lane == 0) ps[wave] = s;
    __syncthreads();
    if (threadIdx.x == 0) {
        wsq[cod] = (ps[0] + ps[1] + ps[2] + ps[3]) * (1.0f / (float)DD);
    }
}

// ---------------------------------------------------------------------------
// Fused kernel, 64 rows/block, 512 thr (8 waves = rg[4 row-strips] x cg[2
// code-strips]). R12 champion structure (175 us) with two deltas:
//  (1) qdist stored FROM THE PV aa FRAGMENTS (wave cg==0, rowg==rg): the
//      bytes were already being read for MFMA — removes the separate
//      et re-read path (2 LDS dword reads/thread/tile, -14% of pass-2 LDS
//      instructions). Identical numerics (same et bf16 values).
//  (2) XCD-aware bijective blockIdx swizzle (grid 1024 % 8 == 0).
// LAUNCH BOUNDS (512,2): NEVER min-waves=4 — allocator drops to the 64-VGPR
// tier and spills epk wholesale (R10/R11/R15/R19, 4x confirmed).
// ---------------------------------------------------------------------------
__global__ __launch_bounds__(512, 2) void fused_kernel(
    const float* __restrict__ x, const short* __restrict__ wbf,
    const short* __restrict__ wtbf, const float* __restrict__ wsq,
    float* __restrict__ qdist, float* __restrict__ quant)
{
    __shared__ short wt_[2][32 * DD];     // 16 KB each: [code][256 d], swizzled
    __shared__ short wtT_[2][128 * 64];   // 16 KB each: superrow layout, swizzled
    __shared__ short et_[2][64 * 36];     // 4.6 KB each: q bf16 [row][32+4pad]
    __shared__ float red_[2][64];
    __shared__ float invs_[64];

    const int t   = threadIdx.x;
    const int w   = t >> 6, l = t & 63;
    const int lhi = l >> 4, llo = l & 15;
    const int rg  = w >> 1, cg = w & 1;

    // XCD-aware bijective swizzle (gridDim.x = 1024, divisible by 8)
    int bid = (int)blockIdx.x;
    {
        const int nwg = (int)gridDim.x;
        if ((nwg & 7) == 0) bid = (bid & 7) * (nwg >> 3) + (bid >> 3);
    }
    const long rowbase = (long)bid * 64;

    // staging thread identities
    const int sc  = t >> 4;              // wt: code 0..31
    const int sg0 = (t & 15) * 2;        // wt: first granule (even)
    const int sd  = t >> 1;              // wtT: d 0..255
    const int sg2 = (t & 1) * 2;         // wtT: granule pair in subrow
    const int ssr = sd >> 1;             // superrow
    const int shb = (sd & 1) * 4;

    bf16x8 wpf0, wpf1;
    float wscur, wsnext;

    // ---- issue wt tile0 loads ----
    { const short* p = wbf + (size_t)sc * DD + sg0 * 8;
      wpf0 = *(const bf16x8*)p; wpf1 = *(const bf16x8*)(p + 8); }

    // ---- x fragments (registers, pass-1 only) ----
    bf16x8 xa[8];
    {
        const float* xr = x + (rowbase + rg * 16 + llo) * DD + lhi * 8;
        #pragma unroll
        for (int kk = 0; kk < 8; kk++) {
            f32x4 v0 = *(const f32x4*)(xr + kk * 32);
            f32x4 v1 = *(const f32x4*)(xr + kk * 32 + 4);
            bf16x8 b;
            b[0]=f2bf(v0[0]); b[1]=f2bf(v0[1]); b[2]=f2bf(v0[2]); b[3]=f2bf(v0[3]);
            b[4]=f2bf(v1[0]); b[5]=f2bf(v1[1]); b[6]=f2bf(v1[2]); b[7]=f2bf(v1[3]);
            xa[kk] = b;
        }
    }

    // ---- stage wt tile0; load wt tile1; wsq ----
    *(bf16x8*)((char*)wt_[0] + sc*512 + (((sg0    ) ^ (sc&7)) << 4)) = wpf0;
    *(bf16x8*)((char*)wt_[0] + sc*512 + (((sg0 + 1) ^ (sc&7)) << 4)) = wpf1;
    { const short* p = wbf + (size_t)(32 + sc) * DD + sg0 * 8;
      wpf0 = *(const bf16x8*)p; wpf1 = *(const bf16x8*)(p + 8); }
    wscur  = wsq[cg * 16 + llo];
    wsnext = wsq[32 + cg * 16 + llo];

    const int  mycode = cg * 16 + llo;
    const int  cswz   = mycode & 7;
    char* const wtb0  = (char*)wt_[0] + mycode * 512;
    char* const wtb1  = (char*)wt_[1] + mycode * 512;

    float rs[4] = {0.f, 0.f, 0.f, 0.f};
    unsigned epk[NT][2];                 // packed bf16 e — VGPRs only

    // =================== PASS 1: scores -> e in registers ===================
    #pragma unroll
    for (int i = 0; i < NT; i++) {
        BAR();
        if (i < NT - 1) {               // stage tile i+1 -> wt[(i+1)&1]
            char* wb = (char*)wt_[(i + 1) & 1] + sc * 512;
            *(bf16x8*)(wb + (((sg0    ) ^ (sc&7)) << 4)) = wpf0;
            *(bf16x8*)(wb + (((sg0 + 1) ^ (sc&7)) << 4)) = wpf1;
        }
        if (i < NT - 2) {               // load tile i+2
            const short* p = wbf + (size_t)((i + 2) * 32 + sc) * DD + sg0 * 8;
            wpf0 = *(const bf16x8*)p; wpf1 = *(const bf16x8*)(p + 8);
        }
        char* wb2 = (i & 1) ? wtb1 : wtb0;
        f32x4 sacc = {0.f, 0.f, 0.f, 0.f};
        #pragma unroll
        for (int kk = 0; kk < 8; kk++) {
            bf16x8 bb = *(const bf16x8*)(wb2 + (((kk * 4 + lhi) ^ cswz) << 4));
            sacc = __builtin_amdgcn_mfma_f32_16x16x32_bf16(xa[kk], bb, sacc, 0, 0, 0);
        }
        float e0 = __expf(sacc[0] * (1.0f / 128.0f) - wscur);
        float e1 = __expf(sacc[1] * (1.0f / 128.0f) - wscur);
        float e2 = __expf(sacc[2] * (1.0f / 128.0f) - wscur);
        float e3 = __expf(sacc[3] * (1.0f / 128.0f) - wscur);
        rs[0] += e0; rs[1] += e1; rs[2] += e2; rs[3] += e3;
        epk[i][0] = pk2(e0, e1);
        epk[i][1] = pk2(e2, e3);
        wscur = wsnext;
        if (i < NT - 2) wsnext = wsq[(i + 2) * 32 + cg * 16 + llo];
    }

    // ---- issue wtT tile0 loads early (cover under reduction) ----
    bf16x8 tpf0, tpf1;
    { const short* p = wtbf + (size_t)sd * KC + sg2 * 8;
      tpf0 = *(const bf16x8*)p; tpf1 = *(const bf16x8*)(p + 8); }

    // ---- rowsum reduce -> invs ----
    #pragma unroll
    for (int m = 1; m <= 8; m <<= 1)
        #pragma unroll
        for (int r = 0; r < 4; r++) rs[r] += __shfl_xor(rs[r], m, 64);
    if (llo == 0) {
        #pragma unroll
        for (int r = 0; r < 4; r++) red_[cg][rg * 16 + lhi * 4 + r] = rs[r];
    }
    __syncthreads();
    if (t < 64) invs_[t] = 1.0f / (red_[0][t] + red_[1][t]);
    __syncthreads();

    float inv4[4];
    #pragma unroll
    for (int r = 0; r < 4; r++) inv4[r] = invs_[rg * 16 + lhi * 4 + r];

    f32x4 uacc[4][2];   // transposed PV: D[d-subtile][row-subtile]
    #pragma unroll
    for (int a = 0; a < 4; a++)
        #pragma unroll
        for (int b = 0; b < 2; b++) uacc[a][b] = (f32x4){0.f, 0.f, 0.f, 0.f};

    float* qbase = qdist + rowbase * KC;
    const int myrow0 = rg * 16 + lhi * 4;

    // =================== PASS 2: PV + outputs (1 barrier/tile) ==============
    #pragma unroll
    for (int i = 0; i < NT; i++) {
        const int b = i & 1;
        // q values for tile i (from registers) -> et (normalized bf16)
        {
            float q0 = bf2f((short)(epk[i][0] & 0xffff)) * inv4[0];
            float q1 = bf2f((short)(epk[i][0] >> 16))    * inv4[1];
            float q2 = bf2f((short)(epk[i][1] & 0xffff)) * inv4[2];
            float q3 = bf2f((short)(epk[i][1] >> 16))    * inv4[3];
            et_[b][(myrow0 + 0) * 36 + mycode] = f2bf(q0);
            et_[b][(myrow0 + 1) * 36 + mycode] = f2bf(q1);
            et_[b][(myrow0 + 2) * 36 + mycode] = f2bf(q2);
            et_[b][(myrow0 + 3) * 36 + mycode] = f2bf(q3);
        }
        // stage wtT tile i -> wtT[b]
        {
            char* tb = (char*)wtT_[b] + ssr * 128;
            *(bf16x8*)(tb + (((shb + sg2    ) ^ (ssr & 7)) << 4)) = tpf0;
            *(bf16x8*)(tb + (((shb + sg2 + 1) ^ (ssr & 7)) << 4)) = tpf1;
        }
        if (i < NT - 1) {               // load wtT tile i+1
            const short* p = wtbf + (size_t)sd * KC + (i + 1) * 32 + sg2 * 8;
            tpf0 = *(const bf16x8*)p; tpf1 = *(const bf16x8*)(p + 8);
        }
        BAR();
        // PV from et_[b] + wtT_[b]; qdist stored from the SAME aa fragments
        bf16x8 bb0, bb1;
        {
            const int d0 = w * 32 + llo;
            bb0 = *(const bf16x8*)((char*)wtT_[b] + (d0 >> 1) * 128 +
                    (((((d0 & 1) << 2) + lhi) ^ ((d0 >> 1) & 7)) << 4));
            const int d1 = w * 32 + 16 + llo;
            bb1 = *(const bf16x8*)((char*)wtT_[b] + (d1 >> 1) * 128 +
                    (((((d1 & 1) << 2) + lhi) ^ ((d1 >> 1) & 7)) << 4));
        }
        #pragma unroll
        for (int rowg = 0; rowg < 4; rowg++) {
            bf16x8 aa = *(const bf16x8*)((char*)et_[b] + (rowg * 16 + llo) * 72 + lhi * 16);
            if (cg == 0 && rowg == rg) {
                // aa = q[row = rowg*16+llo][codes i*32 + lhi*8 .. +7]
                // lanes: 4 lhi x 32B = 128 B contiguous per row; 16 rows/wave
                float* qd = qbase + (size_t)(rowg * 16 + llo) * KC + (size_t)i * 32 + lhi * 8;
                f32x4 o0, o1;
                o0[0]=bf2f(aa[0]); o0[1]=bf2f(aa[1]); o0[2]=bf2f(aa[2]); o0[3]=bf2f(aa[3]);
                o1[0]=bf2f(aa[4]); o1[1]=bf2f(aa[5]); o1[2]=bf2f(aa[6]); o1[3]=bf2f(aa[7]);
                *(f32x4*)qd = o0;
                *(f32x4*)(qd + 4) = o1;
            }
            uacc[rowg][0] = __builtin_amdgcn_mfma_f32_16x16x32_bf16(bb0, aa, uacc[rowg][0], 0, 0, 0);
            uacc[rowg][1] = __builtin_amdgcn_mfma_f32_16x16x32_bf16(bb1, aa, uacc[rowg][1], 0, 0, 0);
        }
    }

    // quant stores: uacc[rowg][dg] = D[d][row] -> f32x4 along d (verified map)
    #pragma unroll
    for (int rowg = 0; rowg < 4; rowg++)
        #pragma unroll
        for (int dg = 0; dg < 2; dg++)
            *(f32x4*)(quant + (rowbase + rowg * 16 + llo) * DD + w * 32 + dg * 16 + lhi * 4)
                = uacc[rowg][dg];
}

// ---------------------------------------------------------------------------
extern "C" void kernel_launch(void* const* d_in, const int* in_sizes, int n_in,
                              void* d_out, int out_size, void* d_ws, size_t ws_size,
                              hipStream_t stream) {
    const float* x = (const float*)d_in[0];
    const float* w = (const float*)d_in[1];
    float* out = (float*)d_out;

    const int nrows = in_sizes[0] / DD;          // 65536
    float* quant = out;                          // [nrows][256]
    float* qdist = out + (size_t)nrows * DD;     // [nrows][1024]

    short* wbf  = (short*)d_ws;                  // 1024*256 bf16 = 512 KB
    short* wtbf = wbf + (size_t)KC * DD;         // 256*1024 bf16 = 512 KB
    float* wsq  = (float*)(wtbf + (size_t)DD * KC);  // 1024 fp32

    prep_kernel<<<KC, DD, 0, stream>>>(w, wbf, wtbf, wsq);
    fused_kernel<<<nrows / 64, 512, 0, stream>>>(x, wbf, wtbf, wsq, qdist, quant);
}